// Round 2
// baseline (772.583 us; speedup 1.0000x reference)
//
#include <hip/hip_runtime.h>

// Sylo forward: out[n,o,h,w] = rs[n,o,h] + cs[n,o,w] - P[n,o,h,w] + bias[o], diag=0
//   T[o,c] = L[o,c] @ L[o,c]^T (rank-4, recomputed per tile)
//   P = sum_c X[n,c] .* T[o,c]
//   rs[n,o,h] = sum_{c,r} L[o,c,h,r] * (X[n,c] @ L[o,c])[h,r]
//   cs[n,o,w] = sum_{c,r} L[o,c,w,r] * (X[n,c]^T @ L[o,c])[w,r]
//
// N=8, C_IN=4, C_OUT=64, DIM=512, RANK=4

#define DIMS 512
#define CIN 4
#define COUT 64
#define NB 8
#define RANKS 4

typedef float f32x4 __attribute__((ext_vector_type(4)));  // nontemporal-store-able

// ws layout (floats):
//   Lpk  [CIN][DIM][COUT*RANK]   = 4*512*256 = 524288   (2 MiB)
//   rs   [NB][COUT][DIM]         = 262144               (1 MiB)
//   cs   [NB][COUT][DIM]         = 262144               (1 MiB)
#define LPK_ELEMS (CIN * DIMS * COUT * RANKS)
#define SUMS_ELEMS (NB * COUT * DIMS)

// ---------------------------------------------------------------------------
// Kernel 0: pack L[o][c][k][r] -> Lpk[c][k][o*4+r]  (coalesced writes)
// ---------------------------------------------------------------------------
__global__ __launch_bounds__(256) void pack_L(const float* __restrict__ L,
                                              float* __restrict__ Lpk) {
    int idx = blockIdx.x * 256 + threadIdx.x;   // 524288 total
    int oc = idx & 255;
    int k  = (idx >> 8) & 511;
    int c  = idx >> 17;
    int o = oc >> 2, r = oc & 3;
    Lpk[idx] = L[((o * CIN + c) * DIMS + k) * RANKS + r];
}

// ---------------------------------------------------------------------------
// Kernel 1: rs (mode 0) and cs (mode 1).
// Block: 256 thr; computes G[16 rows][256 oc] over K=512 for each c, then
// per-c epilogue folds in Lmat[c][row][oc] and accumulates into rsacc.
// Thread tile: 4 d-rows x 4 oc (thread's 4 oc = one o's 4 ranks -> no
// cross-thread reduction needed).
// ---------------------------------------------------------------------------
#define XPAD 68   // 16B-aligned float4 rows, 2-way-max LDS bank aliasing

__global__ __launch_bounds__(256) void sums_kernel(const float* __restrict__ X,
                                                   const float* __restrict__ Lpk,
                                                   float* __restrict__ sums) {
    const int mode = blockIdx.y;                 // 0: rs, 1: cs
    const int n    = blockIdx.x >> 5;            // 8
    const int d0   = (blockIdx.x & 31) << 4;     // 32 tiles of 16 rows
    const int t    = threadIdx.x;
    const int lane = t & 63;                     // -> oc0 = 4*lane (o = lane)
    const int drow = (t >> 6) << 2;              // 0,4,8,12 per wave

    __shared__ float Xsm[16 * XPAD];
    const float4* __restrict__ Lpk4 = (const float4*)Lpk;

    float rsacc[4] = {0.f, 0.f, 0.f, 0.f};

    for (int c = 0; c < CIN; ++c) {
        float acc[4][4];
#pragma unroll
        for (int i = 0; i < 4; ++i)
#pragma unroll
            for (int j = 0; j < 4; ++j) acc[i][j] = 0.f;

        const float* __restrict__ Xc = X + (size_t)(n * CIN + c) * DIMS * DIMS;

        for (int k0 = 0; k0 < DIMS; k0 += 64) {
            __syncthreads();  // protect previous tile's reads
            if (mode == 0) {
                // Xsm[dd][kk] = X[n][c][d0+dd][k0+kk]  (coalesced 64-wide)
                int kk = t & 63, dd = t >> 6;
#pragma unroll
                for (int j = 0; j < 4; ++j)
                    Xsm[(dd + 4 * j) * XPAD + kk] = Xc[(d0 + dd + 4 * j) * DIMS + k0 + kk];
            } else {
                // Xsm[dd][kk] = X[n][c][k0+kk][d0+dd]  (16-wide segments)
                int dd = t & 15, kk0 = t >> 4;
#pragma unroll
                for (int j = 0; j < 4; ++j)
                    Xsm[dd * XPAD + kk0 + 16 * j] = Xc[(k0 + kk0 + 16 * j) * DIMS + d0 + dd];
            }
            __syncthreads();

#pragma unroll 2
            for (int k = 0; k < 64; k += 4) {
                float4 lv0 = Lpk4[(c * DIMS + k0 + k + 0) * 64 + lane];
                float4 lv1 = Lpk4[(c * DIMS + k0 + k + 1) * 64 + lane];
                float4 lv2 = Lpk4[(c * DIMS + k0 + k + 2) * 64 + lane];
                float4 lv3 = Lpk4[(c * DIMS + k0 + k + 3) * 64 + lane];
#pragma unroll
                for (int i = 0; i < 4; ++i) {
                    float4 xv = *(const float4*)&Xsm[(drow + i) * XPAD + k];
                    acc[i][0] += xv.x * lv0.x + xv.y * lv1.x + xv.z * lv2.x + xv.w * lv3.x;
                    acc[i][1] += xv.x * lv0.y + xv.y * lv1.y + xv.z * lv2.y + xv.w * lv3.y;
                    acc[i][2] += xv.x * lv0.z + xv.y * lv1.z + xv.z * lv2.z + xv.w * lv3.z;
                    acc[i][3] += xv.x * lv0.w + xv.y * lv1.w + xv.z * lv2.w + xv.w * lv3.w;
                }
            }
        }
        // epilogue: fold L[o,c,row,r] and reduce over this thread's 4 ranks
#pragma unroll
        for (int i = 0; i < 4; ++i) {
            float4 lf = Lpk4[(c * DIMS + d0 + drow + i) * 64 + lane];
            rsacc[i] += lf.x * acc[i][0] + lf.y * acc[i][1] + lf.z * acc[i][2] + lf.w * acc[i][3];
        }
    }

    float* __restrict__ dst = sums + mode * SUMS_ELEMS;
#pragma unroll
    for (int i = 0; i < 4; ++i)
        dst[(n * COUT + lane) * DIMS + d0 + drow + i] = rsacc[i];
}

// ---------------------------------------------------------------------------
// Kernel 2: out[n,o,h,w] = rs + cs - P + bias, zero diagonal.
// Block: fixed o + 64x64 (h,w) tile; T-tile in LDS amortized over all 8 n.
// Grid x = o (fastest) so consecutive blocks share X tiles in L2.
// ---------------------------------------------------------------------------
__global__ __launch_bounds__(256) void final_kernel(const float* __restrict__ X,
                                                    const float* __restrict__ L,
                                                    const float* __restrict__ bias,
                                                    const float* __restrict__ sums,
                                                    float* __restrict__ out) {
    const int o    = blockIdx.x;           // 64
    const int tile = blockIdx.y;           // 64
    const int h0   = (tile & 7) << 6;
    const int w0   = (tile >> 3) << 6;
    const int t    = threadIdx.x;

    __shared__ float Tsm[CIN * 64 * 64];   // 64 KB
    __shared__ float Lhs[CIN * 64 * 5];    // stride-5 on r to spread banks
    __shared__ float Lws[CIN * 64 * 5];

    // stage L fragments for this o / tile
    for (int idx = t; idx < 2 * CIN * 64 * RANKS; idx += 256) {
        int side = idx >> 10;              // 0: h-side, 1: w-side
        int rem  = idx & 1023;
        int c    = rem >> 8;
        int d    = (rem >> 2) & 63;
        int r    = rem & 3;
        int base = side ? w0 : h0;
        float v  = L[((o * CIN + c) * DIMS + base + d) * RANKS + r];
        (side ? Lws : Lhs)[(c * 64 + d) * 5 + r] = v;
    }
    __syncthreads();

    // T[c][hh][ww] = sum_r Lh[hh][r] * Lw[ww][r]
    {
        int ww = t & 63;
        int hb = t >> 6;
        for (int c = 0; c < CIN; ++c) {
#pragma unroll
            for (int i = 0; i < 16; ++i) {
                int hh = hb + 4 * i;
                float s = 0.f;
#pragma unroll
                for (int r = 0; r < RANKS; ++r)
                    s += Lhs[(c * 64 + hh) * 5 + r] * Lws[(c * 64 + ww) * 5 + r];
                Tsm[c * 4096 + hh * 64 + ww] = s;
            }
        }
    }
    __syncthreads();

    const float4* __restrict__ X4   = (const float4*)X;
    const float4* __restrict__ Tsm4 = (const float4*)Tsm;
    f32x4* __restrict__ out4        = (f32x4*)out;
    const float* __restrict__ rs    = sums;
    const float* __restrict__ cs    = sums + SUMS_ELEMS;
    const float b = bias[o];

    const int ww4   = t & 15;   // float4 column within tile
    const int hbase = t >> 4;   // 16 rows per pass

    for (int n = 0; n < NB; ++n) {
#pragma unroll
        for (int i = 0; i < 4; ++i) {
            int hh = hbase + 16 * i;
            int hg = h0 + hh;
            float4 p = {0.f, 0.f, 0.f, 0.f};
#pragma unroll
            for (int c = 0; c < CIN; ++c) {
                float4 xv = X4[((size_t)((n * CIN + c) * DIMS + hg) * DIMS + w0) / 4 + ww4];
                float4 tv = Tsm4[(c * 4096 + hh * 64) / 4 + ww4];
                p.x += xv.x * tv.x;
                p.y += xv.y * tv.y;
                p.z += xv.z * tv.z;
                p.w += xv.w * tv.w;
            }
            float rv = rs[(n * COUT + o) * DIMS + hg] + b;
            float4 cv = *(const float4*)&cs[(n * COUT + o) * DIMS + w0 + 4 * ww4];
            f32x4 ov;
            ov.x = rv + cv.x - p.x;
            ov.y = rv + cv.y - p.y;
            ov.z = rv + cv.z - p.z;
            ov.w = rv + cv.w - p.w;
            int wg = w0 + 4 * ww4;
            if (hg == wg)     ov.x = 0.f;
            if (hg == wg + 1) ov.y = 0.f;
            if (hg == wg + 2) ov.z = 0.f;
            if (hg == wg + 3) ov.w = 0.f;
            __builtin_nontemporal_store(ov,
                &out4[((size_t)((n * COUT + o) * DIMS + hg) * DIMS + w0) / 4 + ww4]);
        }
    }
}

// ---------------------------------------------------------------------------
extern "C" void kernel_launch(void* const* d_in, const int* in_sizes, int n_in,
                              void* d_out, int out_size, void* d_ws, size_t ws_size,
                              hipStream_t stream) {
    (void)in_sizes; (void)n_in; (void)out_size; (void)ws_size;
    const float* X    = (const float*)d_in[0];
    const float* L    = (const float*)d_in[1];
    const float* bias = (const float*)d_in[2];
    float* out = (float*)d_out;
    float* ws  = (float*)d_ws;

    float* Lpk  = ws;                 // 524288 floats
    float* sums = ws + LPK_ELEMS;     // 2 * 262144 floats

    pack_L<<<LPK_ELEMS / 256, 256, 0, stream>>>(L, Lpk);
    sums_kernel<<<dim3(256, 2), 256, 0, stream>>>(X, Lpk, sums);
    final_kernel<<<dim3(64, 64), 256, 0, stream>>>(X, L, bias, sums, out);
}